// Round 2
// baseline (45.571 us; speedup 1.0000x reference)
//
#include <hip/hip_runtime.h>
#include <stdint.h>

// SWF2LUT 4-simplex interpolation, mode 's'.
// img_in: (8,1,513,513) f32, integer values 0..255
// weight: (17^4, 3) f32  -> quantized clip(round(w*127),-127,127)
// out:    (8,1,512,512,3) f32
//
// Key layout idea: the 5 interpolation taps for a pixel are vertices of ONE
// unit 4-cube cell (ia..ia+1, ib..ib+1, ic..ic+1, id..id+1). Pre-expand the
// 17^4-entry table into 16^4 cells x 16 corners x u32(3x int8 packed) = 64 B
// per cell == one cache line. Each pixel then touches exactly one 64B line
// (1 L2 miss + 4 L1 hits) instead of 5 scattered L2 lines.

#define LQ   17
#define L2C  (17 * 17)        // 289
#define L3C  (17 * 17 * 17)   // 4913
#define NENT (L3C * 17)       // 83521
#define NCELL 65536           // 16^4 cells
#define SUMSTRIDE (L3C + L2C + LQ + 1)  // 5220

__device__ __forceinline__ int quant_i8(float x) {
    int q = (int)rintf(x * 127.0f);           // round-half-even == jnp.round
    return min(127, max(-127, q));
}

// ---- pre-kernel: expand weight table into cell-packed 64B lines ----
// one thread per cell; 16 corners, each = 3 quantized int8 packed in a u32.
__global__ __launch_bounds__(256) void build_cells_kernel(
    const float* __restrict__ w, uint32_t* __restrict__ cells) {
    int cell = blockIdx.x * 256 + threadIdx.x;      // 0..65535
    int ia = (cell >> 12) & 15, ib = (cell >> 8) & 15;
    int ic = (cell >> 4) & 15,  id = cell & 15;
    int base = ia * L3C + ib * L2C + ic * LQ + id;
    uint32_t cr[16];
#pragma unroll
    for (int c = 0; c < 16; ++c) {
        // corner c: bit3->a+1, bit2->b+1, bit1->c+1, bit0->d+1
        int off = ((c >> 3) & 1) * L3C + ((c >> 2) & 1) * L2C +
                  ((c >> 1) & 1) * LQ + (c & 1);
        const float* p = w + (size_t)(base + off) * 3;
        int q0 = quant_i8(p[0]);
        int q1 = quant_i8(p[1]);
        int q2 = quant_i8(p[2]);
        cr[c] = (uint32_t)(q0 & 0xFF) | ((uint32_t)(q1 & 0xFF) << 8) |
                ((uint32_t)(q2 & 0xFF) << 16);
    }
    uint4* o = (uint4*)cells + (size_t)cell * 4;    // 64B aligned
    o[0] = make_uint4(cr[0], cr[1], cr[2], cr[3]);
    o[1] = make_uint4(cr[4], cr[5], cr[6], cr[7]);
    o[2] = make_uint4(cr[8], cr[9], cr[10], cr[11]);
    o[3] = make_uint4(cr[12], cr[13], cr[14], cr[15]);
}

// ---- main kernel: one thread = 4 consecutive x pixels ----
__global__ __launch_bounds__(256) void interp_cells_kernel(
    const float* __restrict__ img, const uint32_t* __restrict__ cells,
    float* __restrict__ out) {
    int gid = blockIdx.x * 256 + threadIdx.x;   // 0..524287
    int x0 = (gid & 127) << 2;                  // 0..508 step 4
    int y  = (gid >> 7) & 511;
    int im = gid >> 16;                         // 0..7

    const float* r0 = img + im * (513 * 513) + y * 513 + x0;
    const float* r1 = r0 + 513;
    float v0[5], v1[5];
#pragma unroll
    for (int i = 0; i < 5; ++i) { v0[i] = r0[i]; v1[i] = r1[i]; }

    float res[12];
#pragma unroll
    for (int i = 0; i < 4; ++i) {
        int a = (int)v0[i], b = (int)v0[i + 1];
        int c = (int)v1[i], d = (int)v1[i + 1];
        // cell id = (ia<<12)|(ib<<8)|(ic<<4)|id ; u32 index = cell*16
        int cellbase = ((((a & 0xF0) << 8) | ((b & 0xF0) << 4) |
                         (c & 0xF0) | (d >> 4))) << 4;
        // keys: f*4 + coord_index (distinct; replicates argsort(-tie_key))
        int k0 = ((a & 15) << 2) | 0;
        int k1 = ((b & 15) << 2) | 1;
        int k2 = ((c & 15) << 2) | 2;
        int k3 = ((d & 15) << 2) | 3;
        int t;
        if (k0 < k1) { t = k0; k0 = k1; k1 = t; }
        if (k2 < k3) { t = k2; k2 = k3; k3 = t; }
        if (k0 < k2) { t = k0; k0 = k2; k2 = t; }
        if (k1 < k3) { t = k1; k1 = k3; k3 = t; }
        if (k1 < k2) { t = k1; k1 = k2; k2 = t; }
        int fs0 = k0 >> 2, fs1 = k1 >> 2, fs2 = k2 >> 2, fs3 = k3 >> 2;
        // corner codes: one-hot bit per coord (a=8,b=4,c=2,d=1), OR-accumulated
        int b0 = 8 >> (k0 & 3);
        int b1 = 8 >> (k1 & 3);
        int b2 = 8 >> (k2 & 3);
        int c1 = b0;
        int c2 = b0 | b1;
        int c3 = c2 | b2;
        uint32_t u0 = cells[cellbase];          // corner 0000
        uint32_t u1 = cells[cellbase + c1];
        uint32_t u2 = cells[cellbase + c2];
        uint32_t u3 = cells[cellbase + c3];
        uint32_t u4 = cells[cellbase + 15];     // corner 1111
        int w0 = 16 - fs0, w1 = fs0 - fs1, w2 = fs1 - fs2, w3 = fs2 - fs3,
            w4 = fs3;
#pragma unroll
        for (int ch = 0; ch < 3; ++ch) {
            int sh = 24 - ch * 8;
            int p0 = (int)(u0 << sh) >> 24;
            int p1 = (int)(u1 << sh) >> 24;
            int p2 = (int)(u2 << sh) >> 24;
            int p3 = (int)(u3 << sh) >> 24;
            int p4 = (int)(u4 << sh) >> 24;
            int acc = w0 * p0 + w1 * p1 + w2 * p2 + w3 * p3 + w4 * p4;
            res[i * 3 + ch] = (float)acc * 0.0625f;  // /16 exact
        }
    }

    int opix = ((im * 512 + y) * 512 + x0) * 3;  // multiple of 12 -> 48B aligned
    float4* o = (float4*)(out + opix);
    o[0] = make_float4(res[0], res[1], res[2], res[3]);
    o[1] = make_float4(res[4], res[5], res[6], res[7]);
    o[2] = make_float4(res[8], res[9], res[10], res[11]);
}

// ---- fallback: gather f32 weights, quantize inline (if ws too small) ----
__device__ __forceinline__ float quant1(float x) {
    return fminf(127.0f, fmaxf(-127.0f, rintf(x * 127.0f)));
}

__device__ __forceinline__ int stride_of(int j) {
    return j == 0 ? L3C : (j == 1 ? L2C : (j == 2 ? LQ : 1));
}

__global__ __launch_bounds__(256) void interp_float_kernel(
    const float* __restrict__ img, const float* __restrict__ wgt,
    float* __restrict__ out) {
    int gid = blockIdx.x * 256 + threadIdx.x;
    int x0 = (gid & 127) << 2;
    int y  = (gid >> 7) & 511;
    int im = gid >> 16;

    const float* r0 = img + im * (513 * 513) + y * 513 + x0;
    const float* r1 = r0 + 513;
    float v0[5], v1[5];
#pragma unroll
    for (int i = 0; i < 5; ++i) { v0[i] = r0[i]; v1[i] = r1[i]; }

    float res[12];
#pragma unroll
    for (int i = 0; i < 4; ++i) {
        int a = (int)v0[i], b = (int)v0[i + 1];
        int c = (int)v1[i], d = (int)v1[i + 1];
        int base = (a >> 4) * L3C + (b >> 4) * L2C + (c >> 4) * LQ + (d >> 4);
        int k0 = ((a & 15) << 2) | 0;
        int k1 = ((b & 15) << 2) | 1;
        int k2 = ((c & 15) << 2) | 2;
        int k3 = ((d & 15) << 2) | 3;
        int t;
        if (k0 < k1) { t = k0; k0 = k1; k1 = t; }
        if (k2 < k3) { t = k2; k2 = k3; k3 = t; }
        if (k0 < k2) { t = k0; k0 = k2; k2 = t; }
        if (k1 < k3) { t = k1; k1 = k3; k3 = t; }
        if (k1 < k2) { t = k1; k1 = k2; k2 = t; }
        int fs0 = k0 >> 2, fs1 = k1 >> 2, fs2 = k2 >> 2, fs3 = k3 >> 2;
        int s0 = stride_of(k0 & 3);
        int s1 = stride_of(k1 & 3);
        int s2 = stride_of(k2 & 3);
        int i0 = base;
        int i1 = base + s0;
        int i2 = i1 + s1;
        int i3 = i2 + s2;
        int i4 = base + SUMSTRIDE;
        float w0 = (float)(16 - fs0), w1 = (float)(fs0 - fs1),
              w2 = (float)(fs1 - fs2), w3 = (float)(fs2 - fs3),
              w4 = (float)fs3;
#pragma unroll
        for (int ch = 0; ch < 3; ++ch) {
            float p0 = quant1(wgt[i0 * 3 + ch]);
            float p1 = quant1(wgt[i1 * 3 + ch]);
            float p2 = quant1(wgt[i2 * 3 + ch]);
            float p3 = quant1(wgt[i3 * 3 + ch]);
            float p4 = quant1(wgt[i4 * 3 + ch]);
            float acc = w0 * p0 + w1 * p1 + w2 * p2 + w3 * p3 + w4 * p4;
            res[i * 3 + ch] = acc * 0.0625f;
        }
    }

    int opix = ((im * 512 + y) * 512 + x0) * 3;
    float4* o = (float4*)(out + opix);
    o[0] = make_float4(res[0], res[1], res[2], res[3]);
    o[1] = make_float4(res[4], res[5], res[6], res[7]);
    o[2] = make_float4(res[8], res[9], res[10], res[11]);
}

extern "C" void kernel_launch(void* const* d_in, const int* in_sizes, int n_in,
                              void* d_out, int out_size, void* d_ws,
                              size_t ws_size, hipStream_t stream) {
    const float* img = (const float*)d_in[0];
    const float* wgt = (const float*)d_in[1];
    float* out = (float*)d_out;

    const int n_groups = 8 * 512 * 128;      // 524288 threads, 4 px each
    const int grid = n_groups / 256;         // 2048 blocks

    if (ws_size >= (size_t)NCELL * 64 && d_ws != nullptr) {
        uint32_t* cells = (uint32_t*)d_ws;   // 4 MiB, 64B-aligned
        build_cells_kernel<<<NCELL / 256, 256, 0, stream>>>(wgt, cells);
        interp_cells_kernel<<<grid, 256, 0, stream>>>(img, cells, out);
    } else {
        interp_float_kernel<<<grid, 256, 0, stream>>>(img, wgt, out);
    }
}